// Round 6
// baseline (84.079 us; speedup 1.0000x reference)
//
#include <hip/hip_runtime.h>

#define B 64
#define T 4096
#define AD 1024   // ATTN_RNN_DIM
#define HD 256    // HYPERNET_DIM
#define CH 32
#define KS 31
#define OD 128
#define PADW 15
#define CWN (CH*KS)   // 992
#define TILE_T 32
#define NTILE (T / TILE_T)   // 128
#define PADROW 132           // 128+4: float4-aligned rows, spread banks

// ---------------- Fused hypernet: h = tanh(q@W1^T+b1); cw = h@W2^T+b2;
//                  Gt[b,k*OD+o] = sum_c Wfc[o,c]*cw[c*KS+k]
// one block per batch, 1024 threads (16 waves)
__global__ __launch_bounds__(1024) void k_hyper(const float* __restrict__ q,
        const float* __restrict__ W1, const float* __restrict__ b1,
        const float* __restrict__ W2, const float* __restrict__ b2,
        const float* __restrict__ Wfc, float* __restrict__ Gt) {
    int b = blockIdx.x;
    int tid = threadIdx.x;
    int lane = tid & 63, wv = tid >> 6;
    __shared__ float qs[AD];            // 4 KB
    __shared__ float hs[HD];            // 1 KB
    __shared__ float cws[CWN];          // 3.9 KB
    __shared__ float wfs_t[CH * OD];    // 16 KB, [c][o]

    qs[tid] = q[(size_t)b * AD + tid];
    #pragma unroll
    for (int p = 0; p < 4; ++p) {
        int idx = p * 1024 + tid;
        int o = idx >> 5, c = idx & 31;
        wfs_t[c * OD + o] = Wfc[idx];
    }
    __syncthreads();

    // h: wave wv owns j in [wv*16, wv*16+16); coalesced W1 row reads
    const float4* qs4 = (const float4*)qs;
    #pragma unroll
    for (int i = 0; i < 16; ++i) {
        int j = wv * 16 + i;
        const float4* wr = (const float4*)(W1 + (size_t)j * AD);
        float s = 0.f;
        #pragma unroll
        for (int m = 0; m < 4; ++m) {
            float4 w  = wr[m * 64 + lane];
            float4 qv = qs4[m * 64 + lane];
            s += w.x * qv.x + w.y * qv.y + w.z * qv.z + w.w * qv.w;
        }
        #pragma unroll
        for (int off = 32; off > 0; off >>= 1)
            s += __shfl_down(s, off, 64);
        if (lane == 0) hs[j] = tanhf(s + b1[j]);
    }
    __syncthreads();

    // cw: one 256-dot per thread
    if (tid < CWN) {
        const float4* wr  = (const float4*)(W2 + (size_t)tid * HD);
        const float4* hs4 = (const float4*)hs;
        float s = 0.f;
        #pragma unroll
        for (int m = 0; m < HD / 4; ++m) {
            float4 w = wr[m], hv = hs4[m];
            s += w.x * hv.x + w.y * hv.y + w.z * hv.z + w.w * hv.w;
        }
        cws[tid] = s + b2[tid];
    }
    __syncthreads();

    // G: 3968 outputs
    #pragma unroll
    for (int p = 0; p < 4; ++p) {
        int idx = p * 1024 + tid;
        if (idx < KS * OD) {
            int k = idx >> 7, o = idx & 127;
            float s = 0.f;
            #pragma unroll
            for (int c = 0; c < CH; ++c)
                s += wfs_t[c * OD + o] * cws[c * KS + k];
            Gt[(size_t)b * (KS * OD) + idx] = s;
        }
    }
}

// ---------------- Conv: out[b,t,o] = sum_k Gt[b,k,o]*pa[b,t+k-15] + bfc[o]
__device__ __forceinline__ void compute_chunk(const float* pa, int s0, float base,
                                              const float (&g)[KS], float (&acc)[8]) {
    float pw[40];
    const float4* lp = (const float4*)(pa + s0);   // s0 % 8 == 0 -> aligned
    #pragma unroll
    for (int q4 = 0; q4 < 10; ++q4) {
        float4 v = lp[q4];
        pw[q4*4+0] = v.x; pw[q4*4+1] = v.y; pw[q4*4+2] = v.z; pw[q4*4+3] = v.w;
    }
    #pragma unroll
    for (int tt = 0; tt < 8; ++tt) {
        float a = base;
        #pragma unroll
        for (int k = 0; k < KS; ++k)
            a += g[k] * pw[tt + k];
        acc[tt] = a;
    }
}

__global__ __launch_bounds__(256, 8) void k_conv(const float* __restrict__ pa_g,
        const float* __restrict__ Gt, const float* __restrict__ bfc,
        float* __restrict__ out) {
    // XCD swizzle: 8192 blocks = 8 XCDs x 1024; each XCD gets 8 whole batches
    int bid  = blockIdx.x;
    int sid  = (bid & 7) * (B * NTILE / 8) + (bid >> 3);
    int b    = sid >> 7;          // 128 tiles per b
    int tile = sid & 127;
    int t0   = tile * TILE_T;
    int tid  = threadIdx.x;
    __shared__ float tileo[TILE_T][PADROW];   // 16.9 KB
    __shared__ float pa[TILE_T + 32];         // 64 floats

    if (tid < TILE_T + 30) {
        int gg = t0 + tid - PADW;
        pa[tid] = (gg >= 0 && gg < T) ? pa_g[(size_t)b * T + gg] : 0.f;
    }
    int o = tid & 127, half = tid >> 7;
    float g[KS];
    #pragma unroll
    for (int k = 0; k < KS; ++k)
        g[k] = Gt[(size_t)b * (KS * OD) + k * OD + o];   // coalesced, L2-hot
    float base = bfc[o];
    __syncthreads();

    #pragma unroll
    for (int c = 0; c < 2; ++c) {           // 2 chunks of 8 t's per half
        int s0 = half * 16 + c * 8;
        float acc[8];
        compute_chunk(pa, s0, base, g, acc);
        #pragma unroll
        for (int tt = 0; tt < 8; ++tt)
            tileo[s0 + tt][o] = acc[tt];    // 2-way bank alias: free
    }
    __syncthreads();

    // cooperative vectorized store: 4 iters x (256 thr x 16B) = 16 KB tile
    size_t obase = ((size_t)b * T + t0) * OD;
    #pragma unroll
    for (int it = 0; it < 4; ++it) {
        int flat = it * 1024 + tid * 4;     // tile-flat == global-flat
        int t = flat >> 7, oo = flat & 127;
        float4 v = *(const float4*)&tileo[t][oo];
        *(float4*)(out + obase + flat) = v; // 1KB contiguous per wave-instr
    }
}

extern "C" void kernel_launch(void* const* d_in, const int* in_sizes, int n_in,
                              void* d_out, int out_size, void* d_ws, size_t ws_size,
                              hipStream_t stream) {
    const float* query = (const float*)d_in[0];
    const float* prev  = (const float*)d_in[1];
    const float* W1    = (const float*)d_in[2];
    const float* b1    = (const float*)d_in[3];
    const float* W2    = (const float*)d_in[4];
    const float* b2    = (const float*)d_in[5];
    const float* Wfc   = (const float*)d_in[6];
    const float* bfc   = (const float*)d_in[7];
    float* out = (float*)d_out;

    float* Gt = (float*)d_ws;          // 64*3968 floats

    k_hyper<<<dim3(B), dim3(1024), 0, stream>>>(query, W1, b1, W2, b2, Wfc, Gt);
    k_conv <<<dim3(B * NTILE), dim3(256), 0, stream>>>(prev, Gt, bfc, out);
}

// Round 7
// 55.371 us; speedup vs baseline: 1.5184x; 1.5184x over previous
//
#include <hip/hip_runtime.h>

#define B 64
#define T 4096
#define AD 1024   // ATTN_RNN_DIM
#define HD 256    // HYPERNET_DIM
#define CH 32
#define KS 31
#define OD 128
#define PADW 15
#define CWN (CH*KS)   // 992
#define TILE_T 64
#define NTILE (T / TILE_T)   // 64
#define PADROW 128           // no pad needed: both phases are 2-way (free)

// ---------------- Kernel A: h[b,j] = tanh(dot(query[b,:], W1[j,:]) + b1[j])
__global__ __launch_bounds__(256) void k_hyper1(const float* __restrict__ q,
        const float* __restrict__ W1, const float* __restrict__ b1,
        float* __restrict__ h) {
    int wid  = blockIdx.x * 4 + (threadIdx.x >> 6);
    int lane = threadIdx.x & 63;
    int b = wid >> 8;
    int j = wid & 255;
    const float4* qr = (const float4*)(q  + (size_t)b * AD);
    const float4* wr = (const float4*)(W1 + (size_t)j * AD);
    float s = 0.f;
    #pragma unroll
    for (int m = 0; m < 4; ++m) {
        float4 a = qr[m * 64 + lane];
        float4 w = wr[m * 64 + lane];
        s += a.x * w.x + a.y * w.y + a.z * w.z + a.w * w.w;
    }
    #pragma unroll
    for (int off = 32; off > 0; off >>= 1)
        s += __shfl_down(s, off, 64);
    if (lane == 0) h[b * HD + j] = tanhf(s + b1[j]);
}

// ---------------- Kernel B: cw[b,r] = dot(h[b,:], W2[r,:]) + b2[r]
__global__ __launch_bounds__(256) void k_cw(const float* __restrict__ h,
        const float* __restrict__ W2, const float* __restrict__ b2,
        float* __restrict__ cw) {
    int b   = blockIdx.x >> 2;
    int qtr = blockIdx.x & 3;
    int tid = threadIdx.x;
    __shared__ float hs[HD];
    hs[tid] = h[(size_t)b * HD + tid];
    __syncthreads();
    int r = qtr * 248 + tid;
    if (tid < 248) {
        const float4* wr = (const float4*)(W2 + (size_t)r * HD);
        float s = 0.f;
        #pragma unroll
        for (int m = 0; m < HD / 4; ++m) {
            float4 w = wr[m];
            s += w.x * hs[4*m+0] + w.y * hs[4*m+1]
               + w.z * hs[4*m+2] + w.w * hs[4*m+3];
        }
        cw[(size_t)b * CWN + r] = s + b2[r];
    }
}

// ---------------- Kernel C: Gt[b, k*OD+o] = sum_c Wfc[o,c]*cw[b, c*KS+k]
__global__ __launch_bounds__(256) void k_G(const float* __restrict__ cw,
        const float* __restrict__ Wfc, float* __restrict__ Gt) {
    int b   = blockIdx.x >> 2;
    int qtr = blockIdx.x & 3;
    int tid = threadIdx.x;
    __shared__ float cws[CWN];
    __shared__ float wfs_t[CH * OD];   // [c][o]
    #pragma unroll
    for (int p = 0; p < 4; ++p) {
        int idx = p * 256 + tid;
        if (idx < CWN) cws[idx] = cw[(size_t)b * CWN + idx];
    }
    #pragma unroll
    for (int p = 0; p < 16; ++p) {
        int idx = p * 256 + tid;
        int o = idx >> 5, c = idx & 31;
        wfs_t[c * OD + o] = Wfc[idx];
    }
    __syncthreads();
    if (tid < 248) {
        int base = qtr * 992 + tid * 4;
        #pragma unroll
        for (int j = 0; j < 4; ++j) {
            int idx = base + j;
            int k = idx >> 7, o = idx & 127;
            float s = 0.f;
            #pragma unroll
            for (int c = 0; c < CH; ++c)
                s += wfs_t[c * OD + o] * cws[c * KS + k];
            Gt[(size_t)b * (KS * OD) + idx] = s;
        }
    }
}

// ---------------- Kernel D: out[b,t,o] = sum_k Gt[b,k,o]*pa[b,t+k-15] + bfc[o]
// per-chunk: compute 16 rows into LDS -> barrier -> issue wide stores ->
// continue next chunk's compute while stores drain (no consumer, no vmcnt wait)
__device__ __forceinline__ void compute_chunk(const float* pa, int s0, float base,
                                              const float (&g)[KS], float (&acc)[8]) {
    float pw[40];
    const float4* lp = (const float4*)(pa + s0);   // s0 % 8 == 0 -> aligned
    #pragma unroll
    for (int q4 = 0; q4 < 10; ++q4) {
        float4 v = lp[q4];
        pw[q4*4+0] = v.x; pw[q4*4+1] = v.y; pw[q4*4+2] = v.z; pw[q4*4+3] = v.w;
    }
    #pragma unroll
    for (int tt = 0; tt < 8; ++tt) {
        float a = base;
        #pragma unroll
        for (int k = 0; k < KS; ++k)
            a += g[k] * pw[tt + k];
        acc[tt] = a;
    }
}

__global__ __launch_bounds__(256, 4) void k_conv(const float* __restrict__ pa_g,
        const float* __restrict__ Gt, const float* __restrict__ bfc,
        float* __restrict__ out) {
    // XCD swizzle: grid 4096 = 8 XCDs x 512; each b's 64 tiles stay on one XCD
    int bid  = blockIdx.x;
    int sid  = (bid & 7) * 512 + (bid >> 3);
    int b    = sid >> 6;
    int tile = sid & 63;
    int t0   = tile * TILE_T;
    int tid  = threadIdx.x;
    __shared__ float tileo[TILE_T][PADROW];   // 32 KB
    __shared__ float pa[TILE_T + 32];         // 96 floats

    if (tid < TILE_T + 32) {
        int gg = t0 + tid - PADW;
        pa[tid] = (gg >= 0 && gg < T) ? pa_g[(size_t)b * T + gg] : 0.f;
    }
    int o = tid & 127, half = tid >> 7;
    float g[KS];
    #pragma unroll
    for (int k = 0; k < KS; ++k)
        g[k] = Gt[(size_t)b * (KS * OD) + k * OD + o];   // coalesced, L2-hot
    float base = bfc[o];
    size_t obase = ((size_t)b * T + t0) * OD;
    __syncthreads();

    #pragma unroll
    for (int c = 0; c < 4; ++c) {
        // compute 8 t's for this half (rows half*32+c*8 .. +7)
        int s0 = half * 32 + c * 8;
        float acc[8];
        compute_chunk(pa, s0, base, g, acc);
        #pragma unroll
        for (int tt = 0; tt < 8; ++tt)
            tileo[s0 + tt][o] = acc[tt];       // 2-way bank alias: free
        __syncthreads();
        // store the 16 rows completed this chunk: rows c*8..c*8+7 (half0 part)
        // and 32+c*8..32+c*8+7 (half1 part). 1KB contiguous per wave-instr.
        #pragma unroll
        for (int j = 0; j < 2; ++j) {
            int f  = j * 256 + tid;            // float4 index in the 16-row set
            int rl = f >> 5, c4 = f & 31;      // 32 float4 per row
            int row = (j == 0) ? (c * 8 + rl) : (32 + c * 8 + (rl - 8));
            float4 v = *(const float4*)&tileo[row][c4 * 4];
            *(float4*)(out + obase + (size_t)row * OD + c4 * 4) = v;
        }
        // no barrier after stores: next chunk writes disjoint LDS rows
    }
}

extern "C" void kernel_launch(void* const* d_in, const int* in_sizes, int n_in,
                              void* d_out, int out_size, void* d_ws, size_t ws_size,
                              hipStream_t stream) {
    const float* query = (const float*)d_in[0];
    const float* prev  = (const float*)d_in[1];
    const float* W1    = (const float*)d_in[2];
    const float* b1    = (const float*)d_in[3];
    const float* W2    = (const float*)d_in[4];
    const float* b2    = (const float*)d_in[5];
    const float* Wfc   = (const float*)d_in[6];
    const float* bfc   = (const float*)d_in[7];
    float* out = (float*)d_out;

    float* h  = (float*)d_ws;          // 16384 floats
    float* cw = h + B * HD;            // 63488 floats
    float* Gt = cw + B * CWN;          // 253952 floats

    k_hyper1<<<dim3(4096), dim3(256), 0, stream>>>(query, W1, b1, h);
    k_cw    <<<dim3(B * 4), dim3(256), 0, stream>>>(h, W2, b2, cw);
    k_G     <<<dim3(B * 4), dim3(256), 0, stream>>>(cw, Wfc, Gt);
    k_conv  <<<dim3(B * NTILE), dim3(256), 0, stream>>>(prev, Gt, bfc, out);
}